// Round 1
// 168.113 us; speedup vs baseline: 1.0417x; 1.0417x over previous
//
#include <hip/hip_runtime.h>
#include <math.h>

#define F_DIM 64
#define K_CL 16
#define B_GR 16
#define SROW 72   // padded LDS row stride in f16 (144 B) -- used by k_fused only

typedef _Float16 h16;
using f16x4 = __attribute__((ext_vector_type(4))) _Float16;
using f16x8 = __attribute__((ext_vector_type(8))) _Float16;
using f32x4 = __attribute__((ext_vector_type(4))) float;

// ---------------------------------------------------------------------------
// K1 (fused): unchanged from baseline.
// ---------------------------------------------------------------------------
__global__ __launch_bounds__(256) void k_fused(
    const float* __restrict__ x, const float* __restrict__ W, const float* __restrict__ bvec,
    h16* __restrict__ ssh, float* __restrict__ outx, float* __restrict__ CCb)
{
    __shared__ float Wl[F_DIM * K_CL];
    __shared__ float bl[K_CL];
    __shared__ __align__(16) h16 stage[4][(16 + 16 + 64) * SROW];  // 55.3 KB

    int t = threadIdx.x;
    for (int idx = t; idx < F_DIM * K_CL; idx += 256) Wl[idx] = W[idx];
    if (t < K_CL) bl[t] = bvec[t];
    __syncthreads();

    int wid = t >> 6, lane = t & 63;
    h16* Sg = stage[wid];            // sraw^T  [16][SROW]
    h16* Cg = Sg + 16 * SROW;        // ss^T    [16][SROW]
    h16* Xg = Cg + 16 * SROW;        // x^T     [64][SROW]

    size_t i = (size_t)blockIdx.x * 256 + t;
    float s[16];
#pragma unroll
    for (int k = 0; k < 16; ++k) s[k] = bl[k];

    const float4* xp = reinterpret_cast<const float4*>(x + i * F_DIM);
#pragma unroll
    for (int j = 0; j < 16; ++j) {
        float4 q = xp[j];
        float xf[4] = {q.x, q.y, q.z, q.w};
#pragma unroll
        for (int ff = 0; ff < 4; ++ff) {
            int f = j * 4 + ff;
            float xv = xf[ff];
            Xg[f * SROW + lane] = (h16)xv;           // stage x^T
            const float4* wr = reinterpret_cast<const float4*>(&Wl[f * K_CL]);
            float4 w0 = wr[0], w1 = wr[1], w2 = wr[2], w3 = wr[3];
            s[0]  += xv * w0.x; s[1]  += xv * w0.y; s[2]  += xv * w0.z; s[3]  += xv * w0.w;
            s[4]  += xv * w1.x; s[5]  += xv * w1.y; s[6]  += xv * w1.z; s[7]  += xv * w1.w;
            s[8]  += xv * w2.x; s[9]  += xv * w2.y; s[10] += xv * w2.z; s[11] += xv * w2.w;
            s[12] += xv * w3.x; s[13] += xv * w3.y; s[14] += xv * w3.z; s[15] += xv * w3.w;
        }
    }

    // stage sraw^T
#pragma unroll
    for (int k = 0; k < 16; ++k) Sg[k * SROW + lane] = (h16)s[k];

    // softmax
    float m = s[0];
#pragma unroll
    for (int k = 1; k < 16; ++k) m = fmaxf(m, s[k]);
    float sum = 0.f;
#pragma unroll
    for (int k = 0; k < 16; ++k) { s[k] = __expf(s[k] - m); sum += s[k]; }
    float inv = 1.0f / sum;
#pragma unroll
    for (int k = 0; k < 16; ++k) s[k] *= inv;

    // stage ss^T + global ssh write
    f16x8 h0, h1;
#pragma unroll
    for (int k = 0; k < 8; ++k) { h0[k] = (h16)s[k]; h1[k] = (h16)s[k + 8]; }
#pragma unroll
    for (int k = 0; k < 8; ++k) {
        Cg[k * SROW + lane] = h0[k];
        Cg[(k + 8) * SROW + lane] = h1[k];
    }
    f16x8* hp = reinterpret_cast<f16x8*>(ssh + i * K_CL);
    hp[0] = h0;
    hp[1] = h1;

    // MFMA phase (wave-private LDS, no barrier needed)
    int q4 = lane >> 4, mm = lane & 15;
    f32x4 accO[4] = {{0.f,0.f,0.f,0.f},{0.f,0.f,0.f,0.f},{0.f,0.f,0.f,0.f},{0.f,0.f,0.f,0.f}};
    f32x4 accC = {0.f, 0.f, 0.f, 0.f};
#pragma unroll
    for (int h = 0; h < 2; ++h) {
        f16x8 aO = *(const f16x8*)&Sg[mm * SROW + h * 32 + q4 * 8];
        f16x8 aC = *(const f16x8*)&Cg[mm * SROW + h * 32 + q4 * 8];
        accC = __builtin_amdgcn_mfma_f32_16x16x32_f16(aC, aC, accC, 0, 0, 0);
#pragma unroll
        for (int ft = 0; ft < 4; ++ft) {
            f16x8 bO = *(const f16x8*)&Xg[(ft * 16 + mm) * SROW + h * 32 + q4 * 8];
            accO[ft] = __builtin_amdgcn_mfma_f32_16x16x32_f16(aO, bO, accO[ft], 0, 0, 0);
        }
    }
    __syncthreads();

    // block reduce (reuse staging LDS)
    float* redO = (float*)&stage[0][0];     // 4 x 1024
    float* redC = redO + 4096;              // 4 x 256
#pragma unroll
    for (int ft = 0; ft < 4; ++ft)
#pragma unroll
        for (int rg = 0; rg < 4; ++rg)
            redO[wid * 1024 + (q4 * 4 + rg) * 64 + ft * 16 + mm] = accO[ft][rg];
#pragma unroll
    for (int rg = 0; rg < 4; ++rg)
        redC[wid * 256 + (q4 * 4 + rg) * 16 + mm] = accC[rg];
    __syncthreads();

    int g = blockIdx.x >> 5;    // 32 blocks per graph
#pragma unroll
    for (int it = 0; it < 4; ++it) {
        int idx = t + it * 256;
        float v = redO[idx] + redO[1024 + idx] + redO[2048 + idx] + redO[3072 + idx];
        atomicAdd(outx + g * 1024 + idx, v);
    }
    {
        float v = redC[t] + redC[256 + t] + redC[512 + t] + redC[768 + t];
        atomicAdd(CCb + g * 256 + t, v);
    }
}

// ---------------------------------------------------------------------------
// K2 v2: oadj via MFMA. Per 64-edge tile per wave:
//   - software pipeline: gathers for tile t+1 and edge loads for tile t+2
//     are issued BEFORE computing tile t (counted vmcnt waits keep them in
//     flight across the compute phase).
//   - LDS transpose via ds_read_b64_tr_b16: stage [64 edges][16 clusters]
//     row-major with 4x ds_write_b128 (contiguous), read MFMA fragments with
//     8x tr reads (fixed 16-h16 element stride = one edge row). A and B are
//     read identically, so the k-slot->edge bijection cancels in the MFMA.
//   LDS ops/tile: 36 -> 12 vs baseline; no more 8-way b128 read conflicts.
// ---------------------------------------------------------------------------
__global__ __launch_bounds__(256) void k_edge(
    const int* __restrict__ erow, const int* __restrict__ ecol, const float* __restrict__ ew,
    const h16* __restrict__ ssh, float* __restrict__ oadj,
    int edges_per_block, int edges_per_graph, int nmask)
{
    __shared__ float CCl[256];
    __shared__ __align__(16) h16 stageE[4][2048];   // per wave: A[64][16] + B[64][16] = 4 KB
    int t = threadIdx.x;
    CCl[t] = 0.f;
    __syncthreads();

    int bid = blockIdx.x;
    int xcd = bid & 7;
    int slot = bid >> 3;
    int graph = xcd + 8 * (slot & 1);
    int chunk = slot >> 1;

    int wid = t >> 6, lane = t & 63;
    int q4 = lane >> 4, mm = lane & 15;
    h16* Ag = stageE[wid];

    int epw = edges_per_block >> 2;           // 512 edges per wave
    int nt  = epw >> 6;                       // 8 tiles of 64 edges
    size_t base = (size_t)graph * edges_per_graph
                + (size_t)chunk * edges_per_block
                + (size_t)wid * epw;

    const f16x8* sshp = reinterpret_cast<const f16x8*>(ssh);
    f32x4 acc = {0.f, 0.f, 0.f, 0.f};

    // LDS addressing
    f16x8* Aw = reinterpret_cast<f16x8*>(Ag);   // A rows at e*32B; B buffer at +2048B (idx 128)
    using lds_h16 = __attribute__((address_space(3))) h16;
    unsigned trA = (unsigned)(uintptr_t)(lds_h16*)Ag + (unsigned)(q4 * 256 + mm * 2);

    // per-tile compute: scale A by w, stage, transpose-read, 2 MFMAs
    auto compute_tile = [&](f16x8 a0, f16x8 a1, f16x8 b0, f16x8 b1, float wv) {
        h16 wh = (h16)wv;
#pragma unroll
        for (int k = 0; k < 8; ++k) { a0[k] *= wh; a1[k] *= wh; }
        Aw[lane * 2]       = a0;
        Aw[lane * 2 + 1]   = a1;
        Aw[128 + lane * 2]     = b0;
        Aw[128 + lane * 2 + 1] = b1;

        f16x4 xa0, xa1, xa2, xa3, xb0, xb1, xb2, xb3;
        asm volatile(
            "ds_read_b64_tr_b16 %0, %8\n\t"
            "ds_read_b64_tr_b16 %1, %8 offset:128\n\t"
            "ds_read_b64_tr_b16 %2, %8 offset:2048\n\t"
            "ds_read_b64_tr_b16 %3, %8 offset:2176\n\t"
            "ds_read_b64_tr_b16 %4, %8 offset:1024\n\t"
            "ds_read_b64_tr_b16 %5, %8 offset:1152\n\t"
            "ds_read_b64_tr_b16 %6, %8 offset:3072\n\t"
            "ds_read_b64_tr_b16 %7, %8 offset:3200\n\t"
            "s_waitcnt lgkmcnt(0)"
            : "=&v"(xa0), "=&v"(xa1), "=&v"(xb0), "=&v"(xb1),
              "=&v"(xa2), "=&v"(xa3), "=&v"(xb2), "=&v"(xb3)
            : "v"(trA)
            : "memory");
        __builtin_amdgcn_sched_barrier(0);

        f16x8 afL = __builtin_shufflevector(xa0, xa1, 0, 1, 2, 3, 4, 5, 6, 7);
        f16x8 bfL = __builtin_shufflevector(xb0, xb1, 0, 1, 2, 3, 4, 5, 6, 7);
        f16x8 afH = __builtin_shufflevector(xa2, xa3, 0, 1, 2, 3, 4, 5, 6, 7);
        f16x8 bfH = __builtin_shufflevector(xb2, xb3, 0, 1, 2, 3, 4, 5, 6, 7);
        acc = __builtin_amdgcn_mfma_f32_16x16x32_f16(afL, bfL, acc, 0, 0, 0);
        acc = __builtin_amdgcn_mfma_f32_16x16x32_f16(afH, bfH, acc, 0, 0, 0);
    };

    // ---- pipeline prologue ----
    // edges tile 0
    int rC, cC; float wC;
    {
        size_t e = base + lane;
        rC = erow[e]; cC = ecol[e]; wC = ew[e];
    }
    // gathers tile 0
    size_t ri = 2 * (size_t)(rC & nmask), ci = 2 * (size_t)(cC & nmask);
    f16x8 ca0 = sshp[ri], ca1 = sshp[ri + 1];
    f16x8 cb0 = sshp[ci], cb1 = sshp[ci + 1];
    // edges tile 1
    int rN = 0, cN = 0; float wN = 0.f;
    if (nt > 1) {
        size_t e = base + 64 + lane;
        rN = erow[e]; cN = ecol[e]; wN = ew[e];
    }

    // ---- steady state: prefetch gathers(t+1) + edges(t+2), compute t ----
    for (int tt = 0; tt < nt - 1; ++tt) {
        // issue gathers for tile tt+1 (edge regs loaded one iteration ago)
        size_t rj = 2 * (size_t)(rN & nmask), cj = 2 * (size_t)(cN & nmask);
        f16x8 na0 = sshp[rj], na1 = sshp[rj + 1];
        f16x8 nb0 = sshp[cj], nb1 = sshp[cj + 1];
        // issue edge loads for tile tt+2 (clamped; redundant reload on last iter)
        int t2 = (tt + 2 < nt) ? (tt + 2) : 0;
        size_t e2 = base + (size_t)t2 * 64 + lane;
        int r2 = erow[e2], c2 = ecol[e2];
        float w2 = ew[e2];

        // compute tile tt (waits only on its own gathers; prefetches stay in flight)
        compute_tile(ca0, ca1, cb0, cb1, wC);

        // rotate
        ca0 = na0; ca1 = na1; cb0 = nb0; cb1 = nb1;
        wC = wN;
        rN = r2; cN = c2; wN = w2;
    }
    // ---- epilogue: last tile ----
    compute_tile(ca0, ca1, cb0, cb1, wC);

    // reduce: acc[rg] is oadj[row = q4*4+rg][col = mm] contribution
#pragma unroll
    for (int rg = 0; rg < 4; ++rg)
        atomicAdd(&CCl[(q4 * 4 + rg) * 16 + mm], acc[rg]);
    __syncthreads();
    atomicAdd(oadj + graph * 256 + t, CCl[t]);
}

// ---------------------------------------------------------------------------
// K3: unchanged from baseline.
// ---------------------------------------------------------------------------
__global__ __launch_bounds__(256) void k_final(
    const float* __restrict__ outx, const float* __restrict__ oadj,
    const float* __restrict__ CCb, float* __restrict__ out, int npg)
{
    int t = threadIdx.x;
    int gid = blockIdx.x * 256 + t;
    {
        float v = outx[gid];
        float r = (v > 0.f) ? (1.0507009873554805f * v)
                            : (1.0507009873554805f * 1.6732632423543772f * (__expf(v) - 1.0f));
        out[gid] = r;
    }

    if (blockIdx.x != 0) return;

    int b = t >> 4, k = t & 15;
    const float* oar = oadj + b * 256 + k * 16;
    const float* ccr = CCb + b * 256 + k * 16;

    float rowsum_off = 0.f, trace_c = 0.f, rowsum_all = 0.f, fro2 = 0.f, colsum = 0.f;
    float csv = 0.f;
#pragma unroll
    for (int l = 0; l < 16; ++l) {
        float v = oar[l];
        rowsum_all += v;
        if (l == k) trace_c = v; else rowsum_off += v;
        float c = ccr[l];
        fro2 += c * c;
        csv += c;                              // cluster_size[k] = sum_l CC[k][l]
        colsum += oadj[b * 256 + l * 16 + k];
    }
    float dd = sqrtf(rowsum_off) + 1e-12f;
    __shared__ float ddl[B_GR * K_CL];
    ddl[t] = dd;

    float ds2 = colsum * colsum, cs2 = csv * csv;
    float tr = trace_c, m2 = rowsum_all;
#pragma unroll
    for (int msk = 8; msk >= 1; msk >>= 1) {
        tr   += __shfl_xor(tr,   msk, 16);
        ds2  += __shfl_xor(ds2,  msk, 16);
        cs2  += __shfl_xor(cs2,  msk, 16);
        fro2 += __shfl_xor(fro2, msk, 16);
        m2   += __shfl_xor(m2,   msk, 16);
    }
    float invfro = 1.0f / sqrtf(fro2);
    float osum = 0.f;
#pragma unroll
    for (int l = 0; l < 16; ++l) {
        float v = ccr[l] * invfro - ((l == k) ? 0.25f : 0.f);
        osum += v * v;
    }
#pragma unroll
    for (int msk = 8; msk >= 1; msk >>= 1) osum += __shfl_xor(osum, msk, 16);

    __shared__ float sp_s[B_GR], cl_s[B_GR], or_s[B_GR];
    if (k == 0) {
        sp_s[b] = tr / m2 - ds2 / (m2 * m2);
        cl_s[b] = sqrtf(cs2) / (float)npg * 4.0f - 1.0f;
        or_s[b] = sqrtf(osum);
    }
    __syncthreads();
    if (t == 0) {
        float a = 0.f, c = 0.f, o = 0.f;
        for (int i = 0; i < B_GR; ++i) { a += sp_s[i]; c += cl_s[i]; o += or_s[i]; }
        out[20480] = -a / 16.f;
        out[20481] = c / 16.f;
        out[20482] = o / 16.f;
    }

#pragma unroll
    for (int l = 0; l < 16; ++l) {
        float v = (l == k) ? 0.f : oar[l] / (dd * ddl[b * 16 + l]);
        out[16384 + b * 256 + k * 16 + l] = v;
    }
}

// ---------------------------------------------------------------------------
extern "C" void kernel_launch(void* const* d_in, const int* in_sizes, int n_in,
                              void* d_out, int out_size, void* d_ws, size_t ws_size,
                              hipStream_t stream)
{
    const float* x    = (const float*)d_in[0];
    const float* W    = (const float*)d_in[1];
    const float* bvec = (const float*)d_in[2];
    const float* ew   = (const float*)d_in[3];
    const int* erow   = (const int*)d_in[4];
    const int* ecol   = (const int*)d_in[5];

    int Ntot = in_sizes[0] / F_DIM;           // 131072
    size_t E = (size_t)in_sizes[3];           // 4194304
    int npg  = Ntot / B_GR;                   // 8192
    int edges_per_graph = (int)(E / B_GR);    // 262144
    int nmask = Ntot - 1;

    const int ADJ_BLOCKS = 2048;              // 128 per graph, 8 per CU
    int edges_per_block = (int)(E / ADJ_BLOCKS);          // 2048

    char* ws = (char*)d_ws;
    size_t o = 0;
    h16*   ssh   = (h16*)(ws + o);   o += (size_t)Ntot * 16 * 2;
    size_t zoff = o;
    float* outx  = (float*)(ws + o); o += (size_t)B_GR * 1024 * 4;
    float* oadj  = (float*)(ws + o); o += (size_t)B_GR * 256 * 4;
    float* CCb   = (float*)(ws + o); o += (size_t)B_GR * 256 * 4;

    hipMemsetAsync(ws + zoff, 0, o - zoff, stream);

    k_fused<<<Ntot / 256, 256, 0, stream>>>(x, W, bvec, ssh, outx, CCb);
    k_edge<<<ADJ_BLOCKS, 256, 0, stream>>>(erow, ecol, ew, ssh, oadj,
                                           edges_per_block, edges_per_graph, nmask);
    k_final<<<64, 256, 0, stream>>>(outx, oadj, CCb, (float*)d_out, npg);
}

// Round 2
// 166.937 us; speedup vs baseline: 1.0490x; 1.0070x over previous
//
#include <hip/hip_runtime.h>
#include <math.h>

#define F_DIM 64
#define K_CL 16
#define B_GR 16
#define SROW 72   // padded LDS row stride in f16 (144 B) -- used by k_fused only

typedef _Float16 h16;
using f16x4 = __attribute__((ext_vector_type(4))) _Float16;
using f16x8 = __attribute__((ext_vector_type(8))) _Float16;
using f32x4 = __attribute__((ext_vector_type(4))) float;

// ---------------------------------------------------------------------------
// K1 (fused): unchanged from baseline.
// ---------------------------------------------------------------------------
__global__ __launch_bounds__(256) void k_fused(
    const float* __restrict__ x, const float* __restrict__ W, const float* __restrict__ bvec,
    h16* __restrict__ ssh, float* __restrict__ outx, float* __restrict__ CCb)
{
    __shared__ float Wl[F_DIM * K_CL];
    __shared__ float bl[K_CL];
    __shared__ __align__(16) h16 stage[4][(16 + 16 + 64) * SROW];  // 55.3 KB

    int t = threadIdx.x;
    for (int idx = t; idx < F_DIM * K_CL; idx += 256) Wl[idx] = W[idx];
    if (t < K_CL) bl[t] = bvec[t];
    __syncthreads();

    int wid = t >> 6, lane = t & 63;
    h16* Sg = stage[wid];            // sraw^T  [16][SROW]
    h16* Cg = Sg + 16 * SROW;        // ss^T    [16][SROW]
    h16* Xg = Cg + 16 * SROW;        // x^T     [64][SROW]

    size_t i = (size_t)blockIdx.x * 256 + t;
    float s[16];
#pragma unroll
    for (int k = 0; k < 16; ++k) s[k] = bl[k];

    const float4* xp = reinterpret_cast<const float4*>(x + i * F_DIM);
#pragma unroll
    for (int j = 0; j < 16; ++j) {
        float4 q = xp[j];
        float xf[4] = {q.x, q.y, q.z, q.w};
#pragma unroll
        for (int ff = 0; ff < 4; ++ff) {
            int f = j * 4 + ff;
            float xv = xf[ff];
            Xg[f * SROW + lane] = (h16)xv;           // stage x^T
            const float4* wr = reinterpret_cast<const float4*>(&Wl[f * K_CL]);
            float4 w0 = wr[0], w1 = wr[1], w2 = wr[2], w3 = wr[3];
            s[0]  += xv * w0.x; s[1]  += xv * w0.y; s[2]  += xv * w0.z; s[3]  += xv * w0.w;
            s[4]  += xv * w1.x; s[5]  += xv * w1.y; s[6]  += xv * w1.z; s[7]  += xv * w1.w;
            s[8]  += xv * w2.x; s[9]  += xv * w2.y; s[10] += xv * w2.z; s[11] += xv * w2.w;
            s[12] += xv * w3.x; s[13] += xv * w3.y; s[14] += xv * w3.z; s[15] += xv * w3.w;
        }
    }

    // stage sraw^T
#pragma unroll
    for (int k = 0; k < 16; ++k) Sg[k * SROW + lane] = (h16)s[k];

    // softmax
    float m = s[0];
#pragma unroll
    for (int k = 1; k < 16; ++k) m = fmaxf(m, s[k]);
    float sum = 0.f;
#pragma unroll
    for (int k = 0; k < 16; ++k) { s[k] = __expf(s[k] - m); sum += s[k]; }
    float inv = 1.0f / sum;
#pragma unroll
    for (int k = 0; k < 16; ++k) s[k] *= inv;

    // stage ss^T + global ssh write
    f16x8 h0, h1;
#pragma unroll
    for (int k = 0; k < 8; ++k) { h0[k] = (h16)s[k]; h1[k] = (h16)s[k + 8]; }
#pragma unroll
    for (int k = 0; k < 8; ++k) {
        Cg[k * SROW + lane] = h0[k];
        Cg[(k + 8) * SROW + lane] = h1[k];
    }
    f16x8* hp = reinterpret_cast<f16x8*>(ssh + i * K_CL);
    hp[0] = h0;
    hp[1] = h1;

    // MFMA phase (wave-private LDS, no barrier needed)
    int q4 = lane >> 4, mm = lane & 15;
    f32x4 accO[4] = {{0.f,0.f,0.f,0.f},{0.f,0.f,0.f,0.f},{0.f,0.f,0.f,0.f},{0.f,0.f,0.f,0.f}};
    f32x4 accC = {0.f, 0.f, 0.f, 0.f};
#pragma unroll
    for (int h = 0; h < 2; ++h) {
        f16x8 aO = *(const f16x8*)&Sg[mm * SROW + h * 32 + q4 * 8];
        f16x8 aC = *(const f16x8*)&Cg[mm * SROW + h * 32 + q4 * 8];
        accC = __builtin_amdgcn_mfma_f32_16x16x32_f16(aC, aC, accC, 0, 0, 0);
#pragma unroll
        for (int ft = 0; ft < 4; ++ft) {
            f16x8 bO = *(const f16x8*)&Xg[(ft * 16 + mm) * SROW + h * 32 + q4 * 8];
            accO[ft] = __builtin_amdgcn_mfma_f32_16x16x32_f16(aO, bO, accO[ft], 0, 0, 0);
        }
    }
    __syncthreads();

    // block reduce (reuse staging LDS)
    float* redO = (float*)&stage[0][0];     // 4 x 1024
    float* redC = redO + 4096;              // 4 x 256
#pragma unroll
    for (int ft = 0; ft < 4; ++ft)
#pragma unroll
        for (int rg = 0; rg < 4; ++rg)
            redO[wid * 1024 + (q4 * 4 + rg) * 64 + ft * 16 + mm] = accO[ft][rg];
#pragma unroll
    for (int rg = 0; rg < 4; ++rg)
        redC[wid * 256 + (q4 * 4 + rg) * 16 + mm] = accC[rg];
    __syncthreads();

    int g = blockIdx.x >> 5;    // 32 blocks per graph
#pragma unroll
    for (int it = 0; it < 4; ++it) {
        int idx = t + it * 256;
        float v = redO[idx] + redO[1024 + idx] + redO[2048 + idx] + redO[3072 + idx];
        atomicAdd(outx + g * 1024 + idx, v);
    }
    {
        float v = redC[t] + redC[256 + t] + redC[512 + t] + redC[768 + t];
        atomicAdd(CCb + g * 256 + t, v);
    }
}

// ---------------------------------------------------------------------------
// K2 v3: oadj via MFMA. The kernel is TA line-request bound (~1 line/cy/CU):
// round 0 and round 1 both measured ~137k cycles == the gather request count.
// Fix: pair-split gathers -- 2 lanes per edge, each loading one 16B half of
// the 32B ssh row. Lane pairs hit the SAME cache line inside ONE instruction
// (TA coalesces), so a 64-lane gather covers 32 rows at ~32 line-requests.
// Gather requests per 64-edge tile: 512 -> ~128. Edge idx loads become
// broadcast-pair (erow[base + (lane>>1)]), still ~2 lines/instr.
// LDS content is byte-identical to v2, so the verified tr-read + MFMA path
// is unchanged. 3-stage software pipeline kept.
// ---------------------------------------------------------------------------
__global__ __launch_bounds__(256) void k_edge(
    const int* __restrict__ erow, const int* __restrict__ ecol, const float* __restrict__ ew,
    const h16* __restrict__ ssh, float* __restrict__ oadj,
    int edges_per_block, int edges_per_graph, int nmask)
{
    __shared__ float CCl[256];
    __shared__ __align__(16) h16 stageE[4][2048];   // per wave: A[64][16] + B[64][16] = 4 KB
    int t = threadIdx.x;
    CCl[t] = 0.f;
    __syncthreads();

    int bid = blockIdx.x;
    int xcd = bid & 7;
    int slot = bid >> 3;
    int graph = xcd + 8 * (slot & 1);
    int chunk = slot >> 1;

    int wid = t >> 6, lane = t & 63;
    int q4 = lane >> 4, mm = lane & 15;
    int half = lane & 1, e2l = lane >> 1;   // 2 lanes per edge
    h16* Ag = stageE[wid];

    int epw = edges_per_block >> 2;           // 512 edges per wave
    int nt  = epw >> 6;                       // 8 tiles of 64 edges
    size_t base = (size_t)graph * edges_per_graph
                + (size_t)chunk * edges_per_block
                + (size_t)wid * epw
                + e2l;                        // this lane's edge slot (subtile 0)

    const f16x8* sshp = reinterpret_cast<const f16x8*>(ssh);
    f32x4 acc = {0.f, 0.f, 0.f, 0.f};

    // LDS addressing: A rows [64 edges][16 h16] at 32B stride; B at +2048B.
    f16x8* Aw = reinterpret_cast<f16x8*>(Ag);
    using lds_h16 = __attribute__((address_space(3))) h16;
    unsigned trA = (unsigned)(uintptr_t)(lds_h16*)Ag + (unsigned)(q4 * 256 + mm * 2);

    // per-tile compute: scale A halves by w, stage (contiguous b128 writes),
    // transpose-read, 2 MFMAs. LDS image identical to v2 (verified).
    auto compute_tile = [&](f16x8 a0, f16x8 a1, f16x8 b0, f16x8 b1,
                            float w0v, float w1v) {
        h16 wh0 = (h16)w0v, wh1 = (h16)w1v;
#pragma unroll
        for (int k = 0; k < 8; ++k) { a0[k] *= wh0; a1[k] *= wh1; }
        // lane = e2l*2 + half -> byte (s*32 + e2l)*32 + half*16
        Aw[lane]        = a0;   // subtile 0: edges  0..31
        Aw[64  + lane]  = a1;   // subtile 1: edges 32..63
        Aw[128 + lane]  = b0;
        Aw[192 + lane]  = b1;

        f16x4 xa0, xa1, xa2, xa3, xb0, xb1, xb2, xb3;
        asm volatile(
            "ds_read_b64_tr_b16 %0, %8\n\t"
            "ds_read_b64_tr_b16 %1, %8 offset:128\n\t"
            "ds_read_b64_tr_b16 %2, %8 offset:2048\n\t"
            "ds_read_b64_tr_b16 %3, %8 offset:2176\n\t"
            "ds_read_b64_tr_b16 %4, %8 offset:1024\n\t"
            "ds_read_b64_tr_b16 %5, %8 offset:1152\n\t"
            "ds_read_b64_tr_b16 %6, %8 offset:3072\n\t"
            "ds_read_b64_tr_b16 %7, %8 offset:3200\n\t"
            "s_waitcnt lgkmcnt(0)"
            : "=&v"(xa0), "=&v"(xa1), "=&v"(xb0), "=&v"(xb1),
              "=&v"(xa2), "=&v"(xa3), "=&v"(xb2), "=&v"(xb3)
            : "v"(trA)
            : "memory");
        __builtin_amdgcn_sched_barrier(0);

        f16x8 afL = __builtin_shufflevector(xa0, xa1, 0, 1, 2, 3, 4, 5, 6, 7);
        f16x8 bfL = __builtin_shufflevector(xb0, xb1, 0, 1, 2, 3, 4, 5, 6, 7);
        f16x8 afH = __builtin_shufflevector(xa2, xa3, 0, 1, 2, 3, 4, 5, 6, 7);
        f16x8 bfH = __builtin_shufflevector(xb2, xb3, 0, 1, 2, 3, 4, 5, 6, 7);
        acc = __builtin_amdgcn_mfma_f32_16x16x32_f16(afL, bfL, acc, 0, 0, 0);
        acc = __builtin_amdgcn_mfma_f32_16x16x32_f16(afH, bfH, acc, 0, 0, 0);
    };

    // ---- pipeline prologue ----
    // idx tile 0 (subtiles 0 and 1; both lanes of a pair read the same slot)
    int r0C, c0C, r1C, c1C; float w0C, w1C;
    r0C = erow[base];      c0C = ecol[base];      w0C = ew[base];
    r1C = erow[base + 32]; c1C = ecol[base + 32]; w1C = ew[base + 32];
    // gathers tile 0 (16B half-rows; lane pairs share the cache line)
    f16x8 ca0 = sshp[2 * (size_t)(r0C & nmask) + half];
    f16x8 ca1 = sshp[2 * (size_t)(r1C & nmask) + half];
    f16x8 cb0 = sshp[2 * (size_t)(c0C & nmask) + half];
    f16x8 cb1 = sshp[2 * (size_t)(c1C & nmask) + half];
    // idx tile 1
    int r0N = 0, c0N = 0, r1N = 0, c1N = 0; float w0N = 0.f, w1N = 0.f;
    if (nt > 1) {
        size_t e = base + 64;
        r0N = erow[e];      c0N = ecol[e];      w0N = ew[e];
        r1N = erow[e + 32]; c1N = ecol[e + 32]; w1N = ew[e + 32];
    }

    // ---- steady state: gathers(t+1) + idx(t+2) issued before compute(t) ----
    for (int tt = 0; tt < nt - 1; ++tt) {
        f16x8 na0 = sshp[2 * (size_t)(r0N & nmask) + half];
        f16x8 na1 = sshp[2 * (size_t)(r1N & nmask) + half];
        f16x8 nb0 = sshp[2 * (size_t)(c0N & nmask) + half];
        f16x8 nb1 = sshp[2 * (size_t)(c1N & nmask) + half];
        int t2 = (tt + 2 < nt) ? (tt + 2) : 0;
        size_t e2 = base + (size_t)t2 * 64;
        int r02 = erow[e2],      c02 = ecol[e2];      float w02 = ew[e2];
        int r12 = erow[e2 + 32], c12 = ecol[e2 + 32]; float w12 = ew[e2 + 32];

        compute_tile(ca0, ca1, cb0, cb1, w0C, w1C);

        ca0 = na0; ca1 = na1; cb0 = nb0; cb1 = nb1;
        w0C = w0N; w1C = w1N;
        r0N = r02; c0N = c02; w0N = w02;
        r1N = r12; c1N = c12; w1N = w12;
    }
    // ---- epilogue: last tile ----
    compute_tile(ca0, ca1, cb0, cb1, w0C, w1C);

    // reduce: acc[rg] is oadj[row = q4*4+rg][col = mm] contribution
#pragma unroll
    for (int rg = 0; rg < 4; ++rg)
        atomicAdd(&CCl[(q4 * 4 + rg) * 16 + mm], acc[rg]);
    __syncthreads();
    atomicAdd(oadj + graph * 256 + t, CCl[t]);
}

// ---------------------------------------------------------------------------
// K3: unchanged from baseline.
// ---------------------------------------------------------------------------
__global__ __launch_bounds__(256) void k_final(
    const float* __restrict__ outx, const float* __restrict__ oadj,
    const float* __restrict__ CCb, float* __restrict__ out, int npg)
{
    int t = threadIdx.x;
    int gid = blockIdx.x * 256 + t;
    {
        float v = outx[gid];
        float r = (v > 0.f) ? (1.0507009873554805f * v)
                            : (1.0507009873554805f * 1.6732632423543772f * (__expf(v) - 1.0f));
        out[gid] = r;
    }

    if (blockIdx.x != 0) return;

    int b = t >> 4, k = t & 15;
    const float* oar = oadj + b * 256 + k * 16;
    const float* ccr = CCb + b * 256 + k * 16;

    float rowsum_off = 0.f, trace_c = 0.f, rowsum_all = 0.f, fro2 = 0.f, colsum = 0.f;
    float csv = 0.f;
#pragma unroll
    for (int l = 0; l < 16; ++l) {
        float v = oar[l];
        rowsum_all += v;
        if (l == k) trace_c = v; else rowsum_off += v;
        float c = ccr[l];
        fro2 += c * c;
        csv += c;                              // cluster_size[k] = sum_l CC[k][l]
        colsum += oadj[b * 256 + l * 16 + k];
    }
    float dd = sqrtf(rowsum_off) + 1e-12f;
    __shared__ float ddl[B_GR * K_CL];
    ddl[t] = dd;

    float ds2 = colsum * colsum, cs2 = csv * csv;
    float tr = trace_c, m2 = rowsum_all;
#pragma unroll
    for (int msk = 8; msk >= 1; msk >>= 1) {
        tr   += __shfl_xor(tr,   msk, 16);
        ds2  += __shfl_xor(ds2,  msk, 16);
        cs2  += __shfl_xor(cs2,  msk, 16);
        fro2 += __shfl_xor(fro2, msk, 16);
        m2   += __shfl_xor(m2,   msk, 16);
    }
    float invfro = 1.0f / sqrtf(fro2);
    float osum = 0.f;
#pragma unroll
    for (int l = 0; l < 16; ++l) {
        float v = ccr[l] * invfro - ((l == k) ? 0.25f : 0.f);
        osum += v * v;
    }
#pragma unroll
    for (int msk = 8; msk >= 1; msk >>= 1) osum += __shfl_xor(osum, msk, 16);

    __shared__ float sp_s[B_GR], cl_s[B_GR], or_s[B_GR];
    if (k == 0) {
        sp_s[b] = tr / m2 - ds2 / (m2 * m2);
        cl_s[b] = sqrtf(cs2) / (float)npg * 4.0f - 1.0f;
        or_s[b] = sqrtf(osum);
    }
    __syncthreads();
    if (t == 0) {
        float a = 0.f, c = 0.f, o = 0.f;
        for (int i = 0; i < B_GR; ++i) { a += sp_s[i]; c += cl_s[i]; o += or_s[i]; }
        out[20480] = -a / 16.f;
        out[20481] = c / 16.f;
        out[20482] = o / 16.f;
    }

#pragma unroll
    for (int l = 0; l < 16; ++l) {
        float v = (l == k) ? 0.f : oar[l] / (dd * ddl[b * 16 + l]);
        out[16384 + b * 256 + k * 16 + l] = v;
    }
}

// ---------------------------------------------------------------------------
extern "C" void kernel_launch(void* const* d_in, const int* in_sizes, int n_in,
                              void* d_out, int out_size, void* d_ws, size_t ws_size,
                              hipStream_t stream)
{
    const float* x    = (const float*)d_in[0];
    const float* W    = (const float*)d_in[1];
    const float* bvec = (const float*)d_in[2];
    const float* ew   = (const float*)d_in[3];
    const int* erow   = (const int*)d_in[4];
    const int* ecol   = (const int*)d_in[5];

    int Ntot = in_sizes[0] / F_DIM;           // 131072
    size_t E = (size_t)in_sizes[3];           // 4194304
    int npg  = Ntot / B_GR;                   // 8192
    int edges_per_graph = (int)(E / B_GR);    // 262144
    int nmask = Ntot - 1;

    const int ADJ_BLOCKS = 2048;              // 128 per graph, 8 per CU
    int edges_per_block = (int)(E / ADJ_BLOCKS);          // 2048

    char* ws = (char*)d_ws;
    size_t o = 0;
    h16*   ssh   = (h16*)(ws + o);   o += (size_t)Ntot * 16 * 2;
    size_t zoff = o;
    float* outx  = (float*)(ws + o); o += (size_t)B_GR * 1024 * 4;
    float* oadj  = (float*)(ws + o); o += (size_t)B_GR * 256 * 4;
    float* CCb   = (float*)(ws + o); o += (size_t)B_GR * 256 * 4;

    hipMemsetAsync(ws + zoff, 0, o - zoff, stream);

    k_fused<<<Ntot / 256, 256, 0, stream>>>(x, W, bvec, ssh, outx, CCb);
    k_edge<<<ADJ_BLOCKS, 256, 0, stream>>>(erow, ecol, ew, ssh, oadj,
                                           edges_per_block, edges_per_graph, nmask);
    k_final<<<64, 256, 0, stream>>>(outx, oadj, CCb, (float*)d_out, npg);
}